// Round 1
// 312.614 us; speedup vs baseline: 1.0013x; 1.0013x over previous
//
#include <hip/hip_runtime.h>

typedef unsigned short u16;
typedef unsigned int   u32;
typedef short bf16x8 __attribute__((ext_vector_type(8)));
typedef float f32x4  __attribute__((ext_vector_type(4)));

#define NB  32
#define NQ  1024
#define GS  1024
#define NH  8
#define SCQ (0.25f * 1.4426950408889634f)   /* 1/sqrt(16) * log2(e) */
#define MBIG (-1.0e30f)

#define MFMA16(a, b, c) __builtin_amdgcn_mfma_f32_16x16x32_bf16(a, b, c, 0, 0, 0)

__device__ __forceinline__ u16 f2bf(float f) {  // RNE float->bf16 bits
    u32 u = __float_as_uint(f);
    return (u16)((u + 0x7fffu + ((u >> 16) & 1u)) >> 16);
}
// packed round-half-up: result = bf(a) | bf(b)<<16, 3 VALU ops via v_perm_b32
__device__ __forceinline__ u32 pk2bf(float a, float b) {
    u32 ua = __float_as_uint(a) + 0x8000u;
    u32 ub = __float_as_uint(b) + 0x8000u;
    return __builtin_amdgcn_perm(ub, ua, 0x07060302u);  // bytes [b3 b2 a3 a2]
}

// ---------------------------------------------------------------------------
// Weight prep (256 blocks, 1 elem/thread): Wp[m][i] bf16.
//  m=0..2 (Wq/Wk/Wv [8][128][16]): i = col*128 + k, col=16h+e, k=d; SCQ in m=0.
//  m=3 (Wout [8][16][128]):        i = d*128 + he   (Wob layout for fused out).
// ---------------------------------------------------------------------------
__global__ __launch_bounds__(256) void wprep(const float* __restrict__ Wq,
                                             const float* __restrict__ Wk,
                                             const float* __restrict__ Wv,
                                             const float* __restrict__ Wout,
                                             u16* __restrict__ Wp) {
    int g = blockIdx.x * 256 + threadIdx.x;   // 65536 total
    int m = g >> 14;
    int i = g & 16383;
    const float* src = (m == 0) ? Wq : (m == 1) ? Wk : (m == 2) ? Wv : Wout;
    float sc = (m == 0) ? SCQ : 1.0f;
    float v;
    if (m < 3) { int cc = i >> 7, k = i & 127;  v = src[(cc >> 4) * 2048 + k * 16 + (cc & 15)]; }
    else       { int d  = i >> 7, he = i & 127; v = src[(he >> 4) * 2048 + (he & 15) * 128 + d]; }
    Wp[m * 16384 + i] = f2bf(v * sc);
}

// ---------------------------------------------------------------------------
// MFMA GEMM: C[128x128] = A[128x128] * W^T, K=128 staged once.
// 256 thr = 4 waves; A fp32 -> bf16 in staging; W prepped bf16 (b128 copies).
// Epilogue goes through LDS (reusing As) so ALL global stores are int4:
// MODE 0: bf16 out row-major.
// MODE 2: bf16 out transposed per batch with PERMUTED token slots:
//         Vt_g[b][col][tb'] , tb' = (tb&~31) | 2*(tb&15) | ((tb>>4)&1)
//         (matches flash's interleaved PV key order -> flash stages V by copy)
//         Transpose+permute applied in LDS scatter; global write coalesced.
// ---------------------------------------------------------------------------
template <int MODE>
__device__ __forceinline__ void mgemm(const float* __restrict__ Ain,
                                      const u16* __restrict__ Wpm,
                                      u16* __restrict__ outb,
                                      u16* As, u16* Ws, int row0) {
    const int t    = threadIdx.x;
    const int wv   = t >> 6;
    const int lane = t & 63;
    const int quad = lane >> 4;
    const int c    = lane & 15;

#pragma unroll
    for (int g0 = 0; g0 < 2048; g0 += 256) {
        int g = g0 + t;
        int row = g >> 4, k0 = (g & 15) * 8;
        const float4* ap = (const float4*)&Ain[(size_t)(row0 + row) * 128 + k0];
        float4 a0 = ap[0], a1 = ap[1];
        int4 pk;
        pk.x = (int)pk2bf(a0.x, a0.y);
        pk.y = (int)pk2bf(a0.z, a0.w);
        pk.z = (int)pk2bf(a1.x, a1.y);
        pk.w = (int)pk2bf(a1.z, a1.w);
        *(int4*)&As[row * 136 + k0] = pk;
    }
#pragma unroll
    for (int g0 = 0; g0 < 2048; g0 += 256) {
        int g = g0 + t;
        int cc = g >> 4, k0 = (g & 15) * 8;
        *(int4*)&Ws[cc * 136 + k0] = *(const int4*)&Wpm[cc * 128 + k0];
    }
    __syncthreads();

    const f32x4 zf = {0.f, 0.f, 0.f, 0.f};
    f32x4 acc[2][8];
#pragma unroll
    for (int s = 0; s < 2; ++s)
#pragma unroll
        for (int j = 0; j < 8; ++j) acc[s][j] = zf;

#pragma unroll
    for (int kt = 0; kt < 4; ++kt) {
        bf16x8 af0 = *(const bf16x8*)&As[(wv * 32 + c) * 136 + kt * 32 + quad * 8];
        bf16x8 af1 = *(const bf16x8*)&As[(wv * 32 + 16 + c) * 136 + kt * 32 + quad * 8];
#pragma unroll
        for (int j = 0; j < 8; ++j) {
            bf16x8 bfr = *(const bf16x8*)&Ws[(j * 16 + c) * 136 + kt * 32 + quad * 8];
            acc[0][j] = MFMA16(af0, bfr, acc[0][j]);
            acc[1][j] = MFMA16(af1, bfr, acc[1][j]);
        }
    }

    // ---- epilogue via LDS: scatter bf16 into As, then coalesced int4 out ----
    __syncthreads();                 // all As/Ws reads complete
    u16* Os = As;                    // reuse 128x136 u16
#pragma unroll
    for (int s = 0; s < 2; ++s)
#pragma unroll
        for (int j = 0; j < 8; ++j)
#pragma unroll
            for (int r = 0; r < 4; ++r) {
                int lrow = wv * 32 + s * 16 + quad * 4 + r;
                int col  = j * 16 + c;
                u16 v = f2bf(acc[s][j][r]);
                if (MODE == 0) {
                    Os[lrow * 136 + col] = v;
                } else {
                    int tbp = (lrow & ~31) | (2 * (lrow & 15)) | ((lrow >> 4) & 1);
                    Os[col * 136 + tbp] = v;
                }
            }
    __syncthreads();

    if (MODE == 0) {
#pragma unroll
        for (int it = 0; it < 8; ++it) {
            int chunk = it * 256 + t;           // 2048 int4 chunks
            int lrow = chunk >> 4, c0 = (chunk & 15) * 8;
            *(int4*)&outb[(size_t)(row0 + lrow) * 128 + c0] =
                *(const int4*)&Os[lrow * 136 + c0];
        }
    } else {
        int bI = row0 >> 10, tb0 = row0 & 1023; // 128-aligned -> perm stays local
#pragma unroll
        for (int it = 0; it < 8; ++it) {
            int chunk = it * 256 + t;
            int col = chunk >> 4, t0 = (chunk & 15) * 8;
            *(int4*)&outb[(size_t)bI * (128 * 1024) + (size_t)col * 1024 + tb0 + t0] =
                *(const int4*)&Os[col * 136 + t0];
        }
    }
}

__global__ __launch_bounds__(256, 2) void proj_mfma(const float* __restrict__ q,
                                                    const float* __restrict__ h,
                                                    const u16* __restrict__ Wp,
                                                    u16* __restrict__ Qb,
                                                    u16* __restrict__ Kb,
                                                    u16* __restrict__ Vtg) {
    __shared__ u16 As[128 * 136];
    __shared__ u16 Ws[128 * 136];
    int row0 = blockIdx.x * 128;
    if (blockIdx.y == 0)      mgemm<0>(q, Wp,         Qb,  As, Ws, row0);
    else if (blockIdx.y == 1) mgemm<0>(h, Wp + 16384, Kb,  As, Ws, row0);
    else                      mgemm<2>(h, Wp + 32768, Vtg, As, Ws, row0);
}

// ---------------------------------------------------------------------------
// MFMA flash attention + fused out-projection.
// Block = (batch, 32 q-rows), 512 thr = 8 waves = 8 heads.
// Mask folded into score-MFMA C operand (Mf floats {0,-1e30}).
// V arrives globally pre-permuted -> staging is a straight int4 copy.
// kf read unconditional: safe because Kt pad columns [128,136) are ZEROED
// once at kernel start (uninitialized LDS can hold NaN patterns and
// MFMA 0*NaN = NaN — the R8 bug). qf zeros kill the padded products.
// LDS: 8704+9216+18432+4608 = 40960 B exactly -> 4 blocks/CU.
// ---------------------------------------------------------------------------
__global__ __launch_bounds__(512, 4) void flash_mfma(const u16* __restrict__ Qb,
                                                     const u16* __restrict__ Kb,
                                                     const u16* __restrict__ Vtg,
                                                     const int* __restrict__ mask,
                                                     const u16* __restrict__ Wob,
                                                     float* __restrict__ out) {
    __shared__ u16 Kt[32 * 136];        // [key][dim]; reused as Hs after loop
    __shared__ u16 Vtt[128 * 36];       // [dim][key-slot]
    __shared__ u16 Ps[NH][32 * 36];     // per-wave P [row][key-slot]
    __shared__ float Mf[32 * 36];       // mask addend [key][row'], stride 36

    const int b    = blockIdx.x;
    const int q0   = blockIdx.y * 32;
    const int t    = threadIdx.x;
    const int hh   = t >> 6;
    const int lane = t & 63;
    const int quad = lane >> 4;
    const int c    = lane & 15;

    // zero Kt pad columns [128,136) of all 32 rows (one-time; see header)
    if (t < 128)
        *(u32*)&Kt[(t >> 2) * 136 + 128 + (t & 3) * 2] = 0u;

    const f32x4  zf = {0.f, 0.f, 0.f, 0.f};
    const bf16x8 zb = {0, 0, 0, 0, 0, 0, 0, 0};

    bf16x8 qf[2];
#pragma unroll
    for (int s = 0; s < 2; ++s) {
        qf[s] = zb;
        if (quad < 2)
            qf[s] = *(const bf16x8*)&Qb[((size_t)b * NQ + q0 + s * 16 + c) * 128 +
                                        hh * 16 + quad * 8];
    }

    f32x4 O[2] = {zf, zf};
    float ls[2][4] = {{0.f, 0.f, 0.f, 0.f}, {0.f, 0.f, 0.f, 0.f}};

    // staging indices
    const int skey = t >> 4;            // K: key 0..31, dim octet (t&15)*8
    const int sd0  = (t & 15) * 8;
    const int vdim = t >> 2;            // V: dim 0..127, slot octet (t&3)*8
    const int vs0  = (t & 3) * 8;
    const int mrow = t >> 4;            // M: row 0..31, key pair (t&15)*2
    const int mk0  = (t & 15) * 2;
    const int rp = (mrow & 3) | (((mrow >> 4) & 1) << 2) |
                   (((mrow >> 3) & 1) << 3) | (((mrow >> 2) & 1) << 4);

    const u16* Kptr = &Kb[((size_t)b * GS + skey) * 128 + sd0];
    const u16* Vptr = &Vtg[(size_t)b * (128 * 1024) + (size_t)vdim * 1024 + vs0];
    const int* Mptr = &mask[((size_t)b * NQ + q0 + mrow) * GS + mk0];

    int4 kreg = *(const int4*)Kptr;
    int4 vreg = *(const int4*)Vptr;
    int2 mreg = *(const int2*)Mptr;

    const int mfoff = ((quad >> 1) << 3) | ((quad & 1) << 4);

    for (int g0 = 0; g0 < GS; g0 += 32) {
        __syncthreads();
        *(int4*)&Kt[skey * 136 + sd0] = kreg;
        *(int4*)&Vtt[vdim * 36 + vs0] = vreg;
        Mf[mk0 * 36 + rp]       = mreg.x ? MBIG : 0.f;
        Mf[(mk0 + 1) * 36 + rp] = mreg.y ? MBIG : 0.f;
        __syncthreads();

        if (g0 + 32 < GS) {
            Kptr += 32 * 128;  kreg = *(const int4*)Kptr;
            Vptr += 32;        vreg = *(const int4*)Vptr;
            Mptr += 32;        mreg = *(const int2*)Mptr;
        }

        // scores with mask addend pre-loaded into C
        f32x4 sc[2][2];
#pragma unroll
        for (int kt = 0; kt < 2; ++kt) {
            bf16x8 kf = *(const bf16x8*)&Kt[(kt * 16 + c) * 136 + hh * 16 + quad * 8];
#pragma unroll
            for (int s = 0; s < 2; ++s) {
                f32x4 c0 = *(const f32x4*)&Mf[(kt * 16 + c) * 36 + (s << 2) + mfoff];
                sc[s][kt] = MFMA16(qf[s], kf, c0);
            }
        }
        bf16x8 vf = *(const bf16x8*)&Vtt[(hh * 16 + c) * 36 + quad * 8];

        // softmax: p = exp2(s + madd); masked -> exactly 0
#pragma unroll
        for (int s = 0; s < 2; ++s) {
#pragma unroll
            for (int r = 0; r < 4; ++r) {
                float e0 = exp2f(sc[s][0][r]);   // key c    -> slot 2c lo
                float e1 = exp2f(sc[s][1][r]);   // key 16+c -> slot 2c hi
                ls[s][r] += e0 + e1;
                int row = s * 16 + quad * 4 + r;
                *(u32*)&Ps[hh][row * 36 + 2 * c] = pk2bf(e0, e1);
            }
        }

        // PV in permuted key order (matches Vtt slots)
#pragma unroll
        for (int s = 0; s < 2; ++s) {
            bf16x8 pf = *(const bf16x8*)&Ps[hh][(s * 16 + c) * 36 + quad * 8];
            O[s] = MFMA16(pf, vf, O[s]);
        }
    }

    // l-reduction, heads -> LDS (reuse Kt as Hs, stride 136)
    float rl[2][4];
#pragma unroll
    for (int s = 0; s < 2; ++s)
#pragma unroll
        for (int r = 0; r < 4; ++r) {
            float l = ls[s][r];
            l += __shfl_xor(l, 1);
            l += __shfl_xor(l, 2);
            l += __shfl_xor(l, 4);
            l += __shfl_xor(l, 8);
            rl[s][r] = (l > 0.f) ? 1.f / l : 0.f;
        }
    __syncthreads();
    u16* Hs = Kt;
#pragma unroll
    for (int s = 0; s < 2; ++s)
#pragma unroll
        for (int r = 0; r < 4; ++r)
            Hs[(s * 16 + quad * 4 + r) * 136 + hh * 16 + c] = f2bf(O[s][r] * rl[s][r]);
    __syncthreads();

    // fused out-projection: wave hh computes out cols hh*16..+15
    f32x4 oacc[2] = {zf, zf};
#pragma unroll
    for (int kt = 0; kt < 4; ++kt) {
        bf16x8 bfr = *(const bf16x8*)&Wob[(hh * 16 + c) * 128 + kt * 32 + quad * 8];
#pragma unroll
        for (int s = 0; s < 2; ++s) {
            bf16x8 af = *(const bf16x8*)&Hs[(s * 16 + c) * 136 + kt * 32 + quad * 8];
            oacc[s] = MFMA16(af, bfr, oacc[s]);
        }
    }
#pragma unroll
    for (int s = 0; s < 2; ++s)
#pragma unroll
        for (int r = 0; r < 4; ++r)
            out[((size_t)b * NQ + q0 + s * 16 + quad * 4 + r) * 128 + hh * 16 + c] =
                oacc[s][r];
}

extern "C" void kernel_launch(void* const* d_in, const int* in_sizes, int n_in,
                              void* d_out, int out_size, void* d_ws, size_t ws_size,
                              hipStream_t stream) {
    const float* q    = (const float*)d_in[0];
    const float* h    = (const float*)d_in[1];
    const int*   mask = (const int*)d_in[2];
    const float* Wq   = (const float*)d_in[3];
    const float* Wk   = (const float*)d_in[4];
    const float* Wv   = (const float*)d_in[5];
    const float* Wout = (const float*)d_in[6];
    float* out = (float*)d_out;

    const size_t NTOK = (size_t)NB * NQ;     // 32768
    u16* Qb  = (u16*)d_ws;                   // 8 MB each
    u16* Kb  = Qb + NTOK * 128;
    u16* Vtg = Kb + NTOK * 128;              // V transposed+permuted per batch
    u16* Wp  = Vtg + NTOK * 128;             // prepped weights (incl. Wob), 128 KB

    wprep<<<dim3(256), 256, 0, stream>>>(Wq, Wk, Wv, Wout, Wp);
    proj_mfma<<<dim3(256, 3), 256, 0, stream>>>(q, h, Wp, Qb, Kb, Vtg);
    flash_mfma<<<dim3(NB, NQ / 32), 512, 0, stream>>>(Qb, Kb, Vtg, mask,
                                                      Wp + 49152, out);
}